// Round 1
// baseline (272.545 us; speedup 1.0000x reference)
//
#include <hip/hip_runtime.h>
#include <hip/hip_bf16.h>

// QHNet block-linear layer: out[b] (40x40) = structured blocks from
//   C0  = x0 (128) @ W0T^T (128x320)   [blk00 cols 0..255 | r011 cols 256..319]
//   C1k = x1[:, :, k] (64) @ W1T^T (64x320), k=0..2
//         [blk01 cols 0..127 | blk10 cols 128..255 | w111-t cols 256..319]
// All 1/N scale factors folded into bf16 weights at prep time.

typedef short bf16x8 __attribute__((ext_vector_type(8)));
typedef float f32x4 __attribute__((ext_vector_type(4)));

static __device__ __forceinline__ unsigned short f2bf(float f) {
    __hip_bfloat16 h = __float2bfloat16(f);
    union { __hip_bfloat16 h; unsigned short u; } cvt; cvt.h = h;
    return cvt.u;
}

// ---- weight prep: transpose to W[n][k] bf16 with scales folded -------------
__global__ void prep_w(const float* __restrict__ w,
                       unsigned short* __restrict__ w0t,
                       unsigned short* __restrict__ w1t) {
    int idx = blockIdx.x * 256 + threadIdx.x;   // 240*256 == 61440 exactly
    const float S000 = 1.0f / 128.0f;
    const float S011 = 1.0f / (128.0f * 1.7320508075688772f);
    const float S1X  = 1.0f / (64.0f * 1.7320508075688772f);
    const float S111 = 1.0f / (64.0f * 2.449489742783178f);
    if (idx < 320 * 128) {
        int n = idx >> 7, k = idx & 127;
        float v;
        if (n < 256) v = w[k * 256 + n] * S000;                 // w000[k][uv]
        else         v = w[32768 + k * 64 + (n - 256)] * S011;  // w011[k][uv]
        w0t[idx] = f2bf(v);
    } else {
        int i2 = idx - 320 * 128;
        int n = i2 >> 6, k = i2 & 63;
        float v;
        if (n < 128)      v = w[40960 + k * 128 + n] * S1X;           // w101
        else if (n < 256) v = w[49152 + k * 128 + (n - 128)] * S1X;   // w110
        else              v = w[57344 + k * 64  + (n - 256)] * S111;  // w111
        w1t[i2] = f2bf(v);
    }
}

// ---- main fused kernel -----------------------------------------------------
// 256 threads = 4 waves; batch tile = 16 rows; wave wv owns an N-slice.
__global__ __launch_bounds__(256) void qhnet_main(
    const float* __restrict__ x_in,
    const unsigned short* __restrict__ w0t,
    const unsigned short* __restrict__ w1t,
    float* __restrict__ out)
{
    __shared__ unsigned short x0L[16 * 128];      // [row][k ^ ((row&7)<<3)]
    __shared__ unsigned short x1L[3][16 * 64];    // [comp][row][w ^ ((row&7)<<3)]

    const int tid = threadIdx.x;
    const int b0 = blockIdx.x * 16;

    // --- stage x tile -> LDS as bf16 (coalesced float4 reads) ---
    const float4* xrow = reinterpret_cast<const float4*>(x_in + (size_t)b0 * 320);
    for (int p = tid; p < 16 * 80; p += 256) {
        int row = p / 80;
        int c4 = p - row * 80;
        float4 v = xrow[p];
        int sw = (row & 7) << 3;
        int col = c4 * 4;
        if (col < 128) {
            int k = col ^ sw;   // XOR-swizzle keeps 4-aligned contiguity
            ushort4 u;
            u.x = f2bf(v.x); u.y = f2bf(v.y); u.z = f2bf(v.z); u.w = f2bf(v.w);
            *reinterpret_cast<ushort4*>(&x0L[row * 128 + k]) = u;
        } else {
            float vv[4] = {v.x, v.y, v.z, v.w};
            #pragma unroll
            for (int e = 0; e < 4; ++e) {
                int f = col - 128 + e;
                int wi = f / 3, cm = f - wi * 3;
                x1L[cm][row * 64 + (wi ^ sw)] = f2bf(vv[e]);
            }
        }
    }
    __syncthreads();

    const int lane = tid & 63;
    const int wv = tid >> 6;        // wave id 0..3 -> N-slice
    const int cn = lane & 15;       // A: batch row in tile; B: col in tile
    const int grp = lane >> 4;      // k-group 0..3
    const int swf = (cn & 7) << 3;

    // --- A fragments from LDS ---
    bf16x8 a0[4], a1[3][2];
    #pragma unroll
    for (int ks = 0; ks < 4; ++ks)
        a0[ks] = *reinterpret_cast<const bf16x8*>(
            &x0L[cn * 128 + ((ks * 32 + grp * 8) ^ swf)]);
    #pragma unroll
    for (int c = 0; c < 3; ++c)
        #pragma unroll
        for (int ks = 0; ks < 2; ++ks)
            a1[c][ks] = *reinterpret_cast<const bf16x8*>(
                &x1L[c][cn * 64 + ((ks * 32 + grp * 8) ^ swf)]);

    f32x4 acc0[5] = {};
    f32x4 acc1[3][5] = {};

    const int c0base[5] = {wv * 64, wv * 64 + 16, wv * 64 + 32, wv * 64 + 48,
                           256 + wv * 16};
    const int c1base[5] = {wv * 32, wv * 32 + 16, 128 + wv * 32,
                           128 + wv * 32 + 16, 256 + wv * 16};

    // --- C0 = X0 @ W0 (K=128) ---
    #pragma unroll
    for (int t = 0; t < 5; ++t) {
        const unsigned short* wp = w0t + (c0base[t] + cn) * 128 + grp * 8;
        #pragma unroll
        for (int ks = 0; ks < 4; ++ks) {
            bf16x8 b = *reinterpret_cast<const bf16x8*>(wp + ks * 32);
            acc0[t] = __builtin_amdgcn_mfma_f32_16x16x32_bf16(a0[ks], b, acc0[t], 0, 0, 0);
        }
    }
    // --- C1k = X1k @ W1 (K=64), B-frag shared across k ---
    #pragma unroll
    for (int t = 0; t < 5; ++t) {
        const unsigned short* wp = w1t + (c1base[t] + cn) * 64 + grp * 8;
        #pragma unroll
        for (int ks = 0; ks < 2; ++ks) {
            bf16x8 b = *reinterpret_cast<const bf16x8*>(wp + ks * 32);
            #pragma unroll
            for (int c = 0; c < 3; ++c)
                acc1[c][t] = __builtin_amdgcn_mfma_f32_16x16x32_bf16(a1[c][ks], b, acc1[c][t], 0, 0, 0);
        }
    }

    // --- epilogue: scatter into 40x40 with eps signs ---
    // C/D frag: row (=batch) = grp*4 + r, col (=n) = cn   [m89 verified]
    float* outw = out + (size_t)(b0 + grp * 4) * 1600;

    #pragma unroll
    for (int t = 0; t < 4; ++t) {               // blk00: u = wv*4+t, v = cn
        int u = wv * 4 + t;
        #pragma unroll
        for (int r = 0; r < 4; ++r)
            outw[(size_t)r * 1600 + u * 40 + cn] = acc0[t][r];
    }

    #pragma unroll
    for (int t = 0; t < 2; ++t) {               // blk01 + blk10
        int n01 = wv * 32 + t * 16 + cn;
        int u01 = n01 >> 3, v01 = n01 & 7;      // blk01: (u<16, v<8)
        int u10 = n01 >> 4, v10 = n01 & 15;     // blk10: (u<8,  v<16)
        #pragma unroll
        for (int r = 0; r < 4; ++r) {
            float* o01 = &outw[(size_t)r * 1600 + u01 * 40 + 16 + 3 * v01];
            o01[0] = acc1[0][t][r];
            o01[1] = acc1[1][t][r];
            o01[2] = acc1[2][t][r];
            #pragma unroll
            for (int c = 0; c < 3; ++c)
                outw[(size_t)r * 1600 + (16 + 3 * u10 + c) * 40 + v10] = acc1[c][t + 2][r];
        }
    }

    {                                           // blk11: diag r011 + eps*t_k
        int uv = wv * 16 + cn, u = uv >> 3, v = uv & 7;
        #pragma unroll
        for (int r = 0; r < 4; ++r) {
            float d  = acc0[4][r];
            float t0 = acc1[0][4][r], t1 = acc1[1][4][r], t2 = acc1[2][4][r];
            float* o = &outw[(size_t)r * 1600 + (16 + 3 * u) * 40 + 16 + 3 * v];
            o[0]  = d;    o[1]  = t2;   o[2]  = -t1;
            o[40] = -t2;  o[41] = d;    o[42] = t0;
            o[80] = t1;   o[81] = -t0;  o[82] = d;
        }
    }
}

extern "C" void kernel_launch(void* const* d_in, const int* in_sizes, int n_in,
                              void* d_out, int out_size, void* d_ws, size_t ws_size,
                              hipStream_t stream) {
    const float* x_in = (const float*)d_in[0];
    const float* weights = (const float*)d_in[1];
    float* out = (float*)d_out;
    unsigned short* w0t = (unsigned short*)d_ws;            // 320*128 bf16
    unsigned short* w1t = w0t + 320 * 128;                  // 320*64  bf16
    int B = in_sizes[0] / 320;                              // 100000

    prep_w<<<240, 256, 0, stream>>>(weights, w0t, w1t);
    qhnet_main<<<B / 16, 256, 0, stream>>>(x_in, w0t, w1t, out);
}

// Round 2
// 224.394 us; speedup vs baseline: 1.2146x; 1.2146x over previous
//
#include <hip/hip_runtime.h>
#include <hip/hip_bf16.h>

// QHNet block-linear layer: out[b] (40x40) = structured blocks from
//   C0  = x0 (128) @ W0T^T (128x320)   [blk00 cols 0..255 | r011 cols 256..319]
//   C1k = x1[:, :, k] (64) @ W1T^T (64x320), k=0..2
//         [blk01 cols 0..127 | blk10 cols 128..255 | w111-t cols 256..319]
// All 1/N scale factors folded into bf16 weights at prep time.
// R2: epilogue stages 40x40 results in LDS, writes coalesced float4
//     (R1 was scattered-4B-store issue-bound at 272us vs ~125us BW floor).

typedef short bf16x8 __attribute__((ext_vector_type(8)));
typedef float f32x4 __attribute__((ext_vector_type(4)));

static __device__ __forceinline__ unsigned short f2bf(float f) {
    __hip_bfloat16 h = __float2bfloat16(f);
    union { __hip_bfloat16 h; unsigned short u; } cvt; cvt.h = h;
    return cvt.u;
}

// ---- weight prep: transpose to W[n][k] bf16 with scales folded -------------
__global__ void prep_w(const float* __restrict__ w,
                       unsigned short* __restrict__ w0t,
                       unsigned short* __restrict__ w1t) {
    int idx = blockIdx.x * 256 + threadIdx.x;   // 240*256 == 61440 exactly
    const float S000 = 1.0f / 128.0f;
    const float S011 = 1.0f / (128.0f * 1.7320508075688772f);
    const float S1X  = 1.0f / (64.0f * 1.7320508075688772f);
    const float S111 = 1.0f / (64.0f * 2.449489742783178f);
    if (idx < 320 * 128) {
        int n = idx >> 7, k = idx & 127;
        float v;
        if (n < 256) v = w[k * 256 + n] * S000;                 // w000[k][uv]
        else         v = w[32768 + k * 64 + (n - 256)] * S011;  // w011[k][uv]
        w0t[idx] = f2bf(v);
    } else {
        int i2 = idx - 320 * 128;
        int n = i2 >> 6, k = i2 & 63;
        float v;
        if (n < 128)      v = w[40960 + k * 128 + n] * S1X;           // w101
        else if (n < 256) v = w[49152 + k * 128 + (n - 128)] * S1X;   // w110
        else              v = w[57344 + k * 64  + (n - 256)] * S111;  // w111
        w1t[i2] = f2bf(v);
    }
}

// ---- main fused kernel -----------------------------------------------------
// 256 threads = 4 waves; batch tile = 16 rows; wave wv owns an N-slice.
__global__ __launch_bounds__(256) void qhnet_main(
    const float* __restrict__ x_in,
    const unsigned short* __restrict__ w0t,
    const unsigned short* __restrict__ w1t,
    float* __restrict__ out)
{
    // 51200 B shared buffer: first aliased as bf16 x-staging (10240 B),
    // then reused as 8-row f32 output tile [8][1600].
    __shared__ __attribute__((aligned(16))) float smemf[8 * 1600];
    unsigned short* x0L = reinterpret_cast<unsigned short*>(smemf); // [16][128]
    unsigned short* x1L = x0L + 16 * 128;                           // [3][16][64]

    const int tid = threadIdx.x;
    const int b0 = blockIdx.x * 16;

    // --- stage x tile -> LDS as bf16 (coalesced float4 reads) ---
    const float4* xrow = reinterpret_cast<const float4*>(x_in + (size_t)b0 * 320);
    for (int p = tid; p < 16 * 80; p += 256) {
        int row = p / 80;
        int c4 = p - row * 80;
        float4 v = xrow[p];
        int sw = (row & 7) << 3;
        int col = c4 * 4;
        if (col < 128) {
            int k = col ^ sw;   // XOR-swizzle keeps 4-aligned contiguity
            ushort4 u;
            u.x = f2bf(v.x); u.y = f2bf(v.y); u.z = f2bf(v.z); u.w = f2bf(v.w);
            *reinterpret_cast<ushort4*>(&x0L[row * 128 + k]) = u;
        } else {
            float vv[4] = {v.x, v.y, v.z, v.w};
            #pragma unroll
            for (int e = 0; e < 4; ++e) {
                int f = col - 128 + e;
                int wi = f / 3, cm = f - wi * 3;
                x1L[cm * 1024 + row * 64 + (wi ^ sw)] = f2bf(vv[e]);
            }
        }
    }
    __syncthreads();

    const int lane = tid & 63;
    const int wv = tid >> 6;        // wave id 0..3 -> N-slice
    const int cn = lane & 15;       // A: batch row in tile; B: col in tile
    const int grp = lane >> 4;      // k-group 0..3
    const int swf = (cn & 7) << 3;

    // --- A fragments from LDS ---
    bf16x8 a0[4], a1[3][2];
    #pragma unroll
    for (int ks = 0; ks < 4; ++ks)
        a0[ks] = *reinterpret_cast<const bf16x8*>(
            &x0L[cn * 128 + ((ks * 32 + grp * 8) ^ swf)]);
    #pragma unroll
    for (int c = 0; c < 3; ++c)
        #pragma unroll
        for (int ks = 0; ks < 2; ++ks)
            a1[c][ks] = *reinterpret_cast<const bf16x8*>(
                &x1L[c * 1024 + cn * 64 + ((ks * 32 + grp * 8) ^ swf)]);

    f32x4 acc0[5] = {};
    f32x4 acc1[3][5] = {};

    const int c0base[5] = {wv * 64, wv * 64 + 16, wv * 64 + 32, wv * 64 + 48,
                           256 + wv * 16};
    const int c1base[5] = {wv * 32, wv * 32 + 16, 128 + wv * 32,
                           128 + wv * 32 + 16, 256 + wv * 16};

    // --- C0 = X0 @ W0 (K=128) ---
    #pragma unroll
    for (int t = 0; t < 5; ++t) {
        const unsigned short* wp = w0t + (c0base[t] + cn) * 128 + grp * 8;
        #pragma unroll
        for (int ks = 0; ks < 4; ++ks) {
            bf16x8 b = *reinterpret_cast<const bf16x8*>(wp + ks * 32);
            acc0[t] = __builtin_amdgcn_mfma_f32_16x16x32_bf16(a0[ks], b, acc0[t], 0, 0, 0);
        }
    }
    // --- C1k = X1k @ W1 (K=64), B-frag shared across k ---
    #pragma unroll
    for (int t = 0; t < 5; ++t) {
        const unsigned short* wp = w1t + (c1base[t] + cn) * 64 + grp * 8;
        #pragma unroll
        for (int ks = 0; ks < 2; ++ks) {
            bf16x8 b = *reinterpret_cast<const bf16x8*>(wp + ks * 32);
            #pragma unroll
            for (int c = 0; c < 3; ++c)
                acc1[c][t] = __builtin_amdgcn_mfma_f32_16x16x32_bf16(a1[c][ks], b, acc1[c][t], 0, 0, 0);
        }
    }

    // --- epilogue: scatter accs -> LDS (8 rows/phase), then coalesced copy ---
    // C/D frag: row (=batch in tile) = grp*4 + r, col (=n) = cn  [m89 verified]
    const int rbase = (grp & 1) * 4;    // row-in-half base for this lane

    #pragma unroll
    for (int h = 0; h < 2; ++h) {
        __syncthreads();    // h=0: fragment reads done; h=1: phase-0 copy done
        if ((grp >> 1) == h) {
            #pragma unroll
            for (int t = 0; t < 4; ++t) {               // blk00
                int u = wv * 4 + t;
                #pragma unroll
                for (int r = 0; r < 4; ++r)
                    smemf[(rbase + r) * 1600 + u * 40 + cn] = acc0[t][r];
            }
            #pragma unroll
            for (int t = 0; t < 2; ++t) {               // blk01 + blk10
                int n01 = wv * 32 + t * 16 + cn;
                int u01 = n01 >> 3, v01 = n01 & 7;      // blk01: (u<16, v<8)
                int u10 = n01 >> 4, v10 = n01 & 15;     // blk10: (u<8,  v<16)
                #pragma unroll
                for (int r = 0; r < 4; ++r) {
                    float* o01 = &smemf[(rbase + r) * 1600 + u01 * 40 + 16 + 3 * v01];
                    o01[0] = acc1[0][t][r];
                    o01[1] = acc1[1][t][r];
                    o01[2] = acc1[2][t][r];
                    #pragma unroll
                    for (int c = 0; c < 3; ++c)
                        smemf[(rbase + r) * 1600 + (16 + 3 * u10 + c) * 40 + v10] = acc1[c][t + 2][r];
                }
            }
            {                                           // blk11: diag + eps*t_k
                int uv = wv * 16 + cn, u = uv >> 3, v = uv & 7;
                #pragma unroll
                for (int r = 0; r < 4; ++r) {
                    float d  = acc0[4][r];
                    float t0 = acc1[0][4][r], t1 = acc1[1][4][r], t2 = acc1[2][4][r];
                    float* o = &smemf[(rbase + r) * 1600 + (16 + 3 * u) * 40 + 16 + 3 * v];
                    o[0]  = d;    o[1]  = t2;   o[2]  = -t1;
                    o[40] = -t2;  o[41] = d;    o[42] = t0;
                    o[80] = t1;   o[81] = -t0;  o[82] = d;
                }
            }
        }
        __syncthreads();
        // cooperative coalesced copy: 8 rows = 3200 float4
        float4* dst = reinterpret_cast<float4*>(out + (size_t)(b0 + h * 8) * 1600);
        const float4* srcv = reinterpret_cast<const float4*>(smemf);
        for (int p = tid; p < 3200; p += 256)
            dst[p] = srcv[p];
    }
}

extern "C" void kernel_launch(void* const* d_in, const int* in_sizes, int n_in,
                              void* d_out, int out_size, void* d_ws, size_t ws_size,
                              hipStream_t stream) {
    const float* x_in = (const float*)d_in[0];
    const float* weights = (const float*)d_in[1];
    float* out = (float*)d_out;
    unsigned short* w0t = (unsigned short*)d_ws;            // 320*128 bf16
    unsigned short* w1t = w0t + 320 * 128;                  // 320*64  bf16
    int B = in_sizes[0] / 320;                              // 100000

    prep_w<<<240, 256, 0, stream>>>(weights, w0t, w1t);
    qhnet_main<<<B / 16, 256, 0, stream>>>(x_in, w0t, w1t, out);
}